// Round 1
// baseline (316.499 us; speedup 1.0000x reference)
//
#include <hip/hip_runtime.h>
#include <stdint.h>

#define B_ 2
#define S_ 2048
#define E_ 2048
#define H_ 16
#define KV_ 4
#define D_ 128
#define G_ (H_ / KV_)
#define M_ (B_ * S_)   // 4096 rows (b*s)

typedef unsigned short u16;
typedef unsigned int u32;
typedef __bf16 bf16x8 __attribute__((ext_vector_type(8)));
typedef float f32x4 __attribute__((ext_vector_type(4)));

__device__ __forceinline__ u16 f2bf(float f) {
  __bf16 h = (__bf16)f;            // v_cvt RNE
  return *(u16*)&h;
}
__device__ __forceinline__ float bf2f(u16 x) {
  return __uint_as_float(((u32)x) << 16);
}
__device__ __forceinline__ void store_c(u16* p, float v) { *p = f2bf(v); }
__device__ __forceinline__ void store_c(float* p, float v) { *p = v; }

// async global->LDS, 16B per lane; LDS dest = wave-uniform base + lane*16
__device__ __forceinline__ void gload_lds16(const u16* g, u16* lds) {
  __builtin_amdgcn_global_load_lds((const __attribute__((address_space(1))) u32*)g,
                                   (__attribute__((address_space(3))) u32*)lds,
                                   16, 0, 0);
}

// ---------------- elementwise fp32 -> bf16 ----------------
__global__ __launch_bounds__(256) void convert_fp32_bf16(const float4* __restrict__ x,
                                                         uint2* __restrict__ o, int n4) {
  int i = blockIdx.x * 256 + threadIdx.x;
  if (i >= n4) return;
  float4 v = x[i];
  uint2 r;
  r.x = (u32)f2bf(v.x) | ((u32)f2bf(v.y) << 16);
  r.y = (u32)f2bf(v.z) | ((u32)f2bf(v.w) << 16);
  o[i] = r;
}

// ---------------- W (K x N) fp32 -> Wt (N x K) bf16 ----------------
__global__ __launch_bounds__(256) void transpose_conv_w(const float* __restrict__ W,
                                                        u16* __restrict__ Wt,
                                                        int Kdim, int Ndim) {
  __shared__ float tile[32][33];
  int n0 = blockIdx.x * 32, k0 = blockIdx.y * 32;
  int tx = threadIdx.x, ty = threadIdx.y;
#pragma unroll
  for (int i = 0; i < 4; i++) {
    int r = ty + i * 8;
    tile[r][tx] = W[(size_t)(k0 + r) * Ndim + n0 + tx];
  }
  __syncthreads();
#pragma unroll
  for (int i = 0; i < 4; i++) {
    int r = ty + i * 8;
    Wt[(size_t)(n0 + r) * Kdim + k0 + tx] = f2bf(tile[tx][r]);
  }
}

// ---------------- V [B][S][KV][D] -> Vt [B][KV][D][S] (bf16) ----------------
__global__ __launch_bounds__(256) void transpose_v(const u16* __restrict__ V,
                                                   u16* __restrict__ Vt) {
  __shared__ u16 tile[32][33];
  int bkv = blockIdx.z;
  int b = bkv / KV_, kv = bkv % KV_;
  int s0 = blockIdx.x * 32, d0 = blockIdx.y * 32;
  int tx = threadIdx.x, ty = threadIdx.y;
#pragma unroll
  for (int i = 0; i < 4; i++) {
    int r = ty + i * 8;  // s within tile
    tile[r][tx] = V[((size_t)((b * S_ + s0 + r) * KV_ + kv)) * D_ + d0 + tx];
  }
  __syncthreads();
#pragma unroll
  for (int i = 0; i < 4; i++) {
    int r = ty + i * 8;  // d within tile
    Vt[((size_t)(b * KV_ + kv) * D_ + d0 + r) * S_ + s0 + tx] = tile[tx][r];
  }
}

// ---------------- RoPE K + repack [row][KV][128] -> [b][kv][s][128] ----------------
__global__ __launch_bounds__(256) void rope_k_repack(const u16* __restrict__ Kin,
                                                     u16* __restrict__ Kp, int total) {
  int idx = blockIdx.x * 256 + threadIdx.x;
  if (idx >= total) return;
  int d = idx & 63;
  int rem = idx >> 6;
  int kv = rem % KV_;
  int row = rem / KV_;
  int b = row >> 11;           // row / S_
  int spos = row & (S_ - 1);
  size_t src = ((size_t)row * KV_ + kv) * D_ + d;
  float x0 = bf2f(Kin[src]);
  float x1 = bf2f(Kin[src + 64]);
  float ang = (float)spos * expf(-0.14391156831212787f * (float)d);
  float sn, cs;
  sincosf(ang, &sn, &cs);
  size_t dst = ((size_t)((b * KV_ + kv) * S_ + spos)) * D_ + d;
  Kp[dst]      = f2bf(x0 * cs - x1 * sn);
  Kp[dst + 64] = f2bf(x1 * cs + x0 * sn);
}

// =====================================================================
// 256x256 8-phase bf16 GEMM (m201 template, plain HIP):
//   C(MxN) = A(MxK) * Bt(NxK)^T
// 8 waves (2M x 4N), BK=64, per-wave output 128x64.
// LDS 128 KiB: A/B x dbuf(2) x half(2) x [128 rows][64 k] bf16 (16 KiB each).
// Swizzle: 16B-chunk index ^= (row&7)  (applied on read addr AND inverse on
// global source for the linear global_load_lds dest — both-sides rule).
// Counted vmcnt(6) once per K-tile (3 half-tiles in flight); raw barriers;
// lgkmcnt(0) drains before barriers that precede a region's overwrite issue.
// Stage stream per tile kt: ph0:(kt+1)B1  ph1:(kt+2)B0  ph3:(kt+2)A0,(kt+2)A1
// Reads: ph0: all B (8) + A m0-3 (8); ph2: A m4-7 (8, reusing regs).
// =====================================================================
template <typename CT>
__device__ __forceinline__ void gemm256_body(const u16* __restrict__ A,
                                             const u16* __restrict__ Bt,
                                             CT* __restrict__ C,
                                             int Kdim, int Ndim, int m0, int n0) {
  extern __shared__ __align__(16) u16 smem[];   // 65536 u16 = 128 KiB
  const int tid  = threadIdx.x;
  const int lane = tid & 63;
  const int wave = tid >> 6;          // 0..7
  const int wm   = wave >> 2;         // 0..1  M-half of the tile
  const int wn   = wave & 3;          // 0..3  N-quarter
  const int bh   = wn >> 1;           // which B half this wave reads
  const int nb   = (wn & 1) * 64;     // row offset inside B half
  const int quad = lane >> 4, lm = lane & 15;

  // per-thread staging descriptors (same geometry for A and B halves)
  int soff[2], sldb[2];
#pragma unroll
  for (int i = 0; i < 2; i++) {
    int cc  = i * 512 + tid;          // 16B chunk id in [0,1024)
    int row = cc >> 3;                // 8 chunks per 128B row
    int q   = (cc & 7) ^ (row & 7);   // inverse-swizzled source chunk
    soff[i] = row * Kdim + q * 8;     // u16 elements
    sldb[i] = (i * 512 + wave * 64) * 8;  // wave-uniform LDS u16 base
  }
  auto STAGE = [&](const u16* g, u16* l) {
    gload_lds16(g + soff[0], l + sldb[0]);
    gload_lds16(g + soff[1], l + sldb[1]);
  };

  // swizzled read chunk offsets (u16) for ks=0,1
  int cs0 = ((0 + quad) ^ (lm & 7)) * 8;
  int cs1 = ((4 + quad) ^ (lm & 7)) * 8;

  const u16* Ag = A  + (size_t)m0 * Kdim;
  const u16* Bg = Bt + (size_t)n0 * Kdim;
  const size_t hstep = (size_t)128 * Kdim;  // half-tile row step

  // LDS regions (u16 offsets): A: (buf*2+h)*8192 ; B: 32768 + (buf*2+h)*8192
  f32x4 acc[8][4];
  f32x4 zero = {0.f, 0.f, 0.f, 0.f};
#pragma unroll
  for (int m = 0; m < 8; m++)
#pragma unroll
    for (int n = 0; n < 4; n++) acc[m][n] = zero;

  const int NKT = Kdim >> 6;

  // ---- prologue: stream t0{B0,A0,A1,B1} t1{B0,A0,A1} ----
  STAGE(Bg,             smem + 32768 + 0 * 8192);  // t0 B0
  STAGE(Ag,             smem + 0 * 8192);          // t0 A0
  STAGE(Ag + hstep,     smem + 1 * 8192);          // t0 A1
  STAGE(Bg + hstep,     smem + 32768 + 1 * 8192);  // t0 B1
  STAGE(Bg + 64,        smem + 32768 + 2 * 8192);  // t1 B0
  STAGE(Ag + 64,        smem + 2 * 8192);          // t1 A0
  STAGE(Ag + hstep + 64, smem + 3 * 8192);         // t1 A1
  asm volatile("s_waitcnt vmcnt(6)" ::: "memory"); // t0 fully resident (own ops)
  __builtin_amdgcn_s_barrier();                    // -> all waves' ops resident

  for (int kt = 0; kt < NKT; ++kt) {
    const int cur = kt & 1;
    const u16* regA = smem + (cur * 2 + wm) * 8192;
    const u16* regB = smem + 32768 + (cur * 2 + bh) * 8192;
    bf16x8 af[4][2], bf[4][2];

    // ---------- phase 0: read all B + A m0-3 ; stage (kt+1) B1 ----------
#pragma unroll
    for (int n = 0; n < 4; n++) {
      bf[n][0] = *(const bf16x8*)(regB + (nb + n * 16 + lm) * 64 + cs0);
      bf[n][1] = *(const bf16x8*)(regB + (nb + n * 16 + lm) * 64 + cs1);
    }
#pragma unroll
    for (int m = 0; m < 4; m++) {
      af[m][0] = *(const bf16x8*)(regA + (m * 16 + lm) * 64 + cs0);
      af[m][1] = *(const bf16x8*)(regA + (m * 16 + lm) * 64 + cs1);
    }
    if (kt + 1 < NKT)
      STAGE(Bg + hstep + (size_t)(kt + 1) * 64,
            smem + 32768 + (((kt + 1) & 1) * 2 + 1) * 8192);
    asm volatile("s_waitcnt lgkmcnt(0)" ::: "memory");
    __builtin_amdgcn_s_barrier();
    __builtin_amdgcn_s_setprio(1);
#pragma unroll
    for (int m = 0; m < 4; m++)
#pragma unroll
      for (int n = 0; n < 2; n++) {
        acc[m][n] = __builtin_amdgcn_mfma_f32_16x16x32_bf16(af[m][0], bf[n][0], acc[m][n], 0, 0, 0);
        acc[m][n] = __builtin_amdgcn_mfma_f32_16x16x32_bf16(af[m][1], bf[n][1], acc[m][n], 0, 0, 0);
      }
    __builtin_amdgcn_s_setprio(0);
    __builtin_amdgcn_s_barrier();

    // ---------- phase 1: stage (kt+2) B0 ----------
    if (kt + 2 < NKT)
      STAGE(Bg + (size_t)(kt + 2) * 64, smem + 32768 + (cur * 2 + 0) * 8192);
    __builtin_amdgcn_s_barrier();
    __builtin_amdgcn_s_setprio(1);
#pragma unroll
    for (int m = 0; m < 4; m++)
#pragma unroll
      for (int n = 2; n < 4; n++) {
        acc[m][n] = __builtin_amdgcn_mfma_f32_16x16x32_bf16(af[m][0], bf[n][0], acc[m][n], 0, 0, 0);
        acc[m][n] = __builtin_amdgcn_mfma_f32_16x16x32_bf16(af[m][1], bf[n][1], acc[m][n], 0, 0, 0);
      }
    __builtin_amdgcn_s_setprio(0);
    __builtin_amdgcn_s_barrier();

    // ---------- phase 2: read A m4-7 (reuse regs) ----------
#pragma unroll
    for (int m = 0; m < 4; m++) {
      af[m][0] = *(const bf16x8*)(regA + ((m + 4) * 16 + lm) * 64 + cs0);
      af[m][1] = *(const bf16x8*)(regA + ((m + 4) * 16 + lm) * 64 + cs1);
    }
    asm volatile("s_waitcnt lgkmcnt(0)" ::: "memory");
    __builtin_amdgcn_s_barrier();
    __builtin_amdgcn_s_setprio(1);
#pragma unroll
    for (int m = 0; m < 4; m++)
#pragma unroll
      for (int n = 0; n < 2; n++) {
        acc[m + 4][n] = __builtin_amdgcn_mfma_f32_16x16x32_bf16(af[m][0], bf[n][0], acc[m + 4][n], 0, 0, 0);
        acc[m + 4][n] = __builtin_amdgcn_mfma_f32_16x16x32_bf16(af[m][1], bf[n][1], acc[m + 4][n], 0, 0, 0);
      }
    __builtin_amdgcn_s_setprio(0);
    __builtin_amdgcn_s_barrier();

    // ---------- phase 3: stage (kt+2) A0, A1 ; counted vmcnt ----------
    if (kt + 2 < NKT) {
      STAGE(Ag + (size_t)(kt + 2) * 64,         smem + (cur * 2 + 0) * 8192);
      STAGE(Ag + hstep + (size_t)(kt + 2) * 64, smem + (cur * 2 + 1) * 8192);
    }
    __builtin_amdgcn_s_setprio(1);
#pragma unroll
    for (int m = 0; m < 4; m++)
#pragma unroll
      for (int n = 2; n < 4; n++) {
        acc[m + 4][n] = __builtin_amdgcn_mfma_f32_16x16x32_bf16(af[m][0], bf[n][0], acc[m + 4][n], 0, 0, 0);
        acc[m + 4][n] = __builtin_amdgcn_mfma_f32_16x16x32_bf16(af[m][1], bf[n][1], acc[m + 4][n], 0, 0, 0);
      }
    __builtin_amdgcn_s_setprio(0);
    asm volatile("s_waitcnt vmcnt(6)" ::: "memory");  // next tile fully resident
    __builtin_amdgcn_s_barrier();
  }

  // ---------- epilogue: C write ----------
#pragma unroll
  for (int m = 0; m < 8; m++) {
    const int row = m0 + wm * 128 + m * 16 + quad * 4;
#pragma unroll
    for (int n = 0; n < 4; n++) {
      const int col = n0 + wn * 64 + n * 16 + lm;
#pragma unroll
      for (int r = 0; r < 4; r++)
        store_c(C + (size_t)(row + r) * Ndim + col, acc[m][n][r]);
    }
  }
}

// fused Q/K/V projection, 256^2 tiles: x 0..7 -> Q, 8..9 -> K, 10..11 -> V
__global__ __launch_bounds__(512, 2) void gemm256_qkv(const u16* __restrict__ A,
                                                      const u16* __restrict__ WqT,
                                                      const u16* __restrict__ WkT,
                                                      const u16* __restrict__ WvT,
                                                      u16* __restrict__ Qb,
                                                      u16* __restrict__ Kb,
                                                      u16* __restrict__ Vb) {
  int bx = blockIdx.x;
  const u16* Bt;
  u16* C;
  int n0, Ndim;
  if (bx < 8)       { Bt = WqT; C = Qb; n0 = bx * 256;        Ndim = 2048; }
  else if (bx < 10) { Bt = WkT; C = Kb; n0 = (bx - 8) * 256;  Ndim = 512; }
  else              { Bt = WvT; C = Vb; n0 = (bx - 10) * 256; Ndim = 512; }
  gemm256_body<u16>(A, Bt, C, 2048, Ndim, blockIdx.y * 256, n0);
}

__global__ __launch_bounds__(512, 2) void gemm256_wo(const u16* __restrict__ A,
                                                     const u16* __restrict__ Bt,
                                                     float* __restrict__ C) {
  gemm256_body<float>(A, Bt, C, 2048, 2048, blockIdx.y * 256, blockIdx.x * 256);
}

// ---------------- causal GQA flash attention, v5 (unchanged) ----------------
__global__ __launch_bounds__(256, 2) void attn_kernel(const u16* __restrict__ Q,
                                                      const u16* __restrict__ Kp,
                                                      const u16* __restrict__ Vt,
                                                      u16* __restrict__ O) {
  __shared__ __align__(16) u16 Ksh[2][64 * 128];   // 2 x 16 KB
  __shared__ __align__(16) u16 Vsh[128 * 64];      // 16 KB
  __shared__ __align__(16) u16 Psh[4][16 * 64];    // 8 KB, per-wave

  const int tid = threadIdx.x;
  const int lane = tid & 63;
  const int wave = tid >> 6;                       // 0..3
  const int quad = lane >> 4, lm = lane & 15;
  const int b = blockIdx.z, h = blockIdx.y;
  const int kh = h / G_;

  const u16* Kbase = Kp + (size_t)(b * KV_ + kh) * S_ * D_;
  const u16* Vbase = Vt + (size_t)(b * KV_ + kh) * D_ * S_;
  u16* pw = &Psh[wave][0];

  int offK[4], offV[4], ldsOff[4];
#pragma unroll
  for (int i = 0; i < 4; i++) {
    int idx = (wave * 4 + i) * 64 + lane;          // [0,1024) 16B-chunk id
    int rK = idx >> 4;                             // K row (key), 16 chunks/row
    int cK = (idx & 15) ^ (rK & 7);
    offK[i] = rK * 128 + cK * 8;
    int rV = idx >> 3;                             // V^T row (d), 8 chunks/row
    int cV = (idx & 7) ^ (rV & 7);
    offV[i] = rV * S_ + cV * 8;
    ldsOff[i] = (wave * 4 + i) * 512;              // u16
  }

  bf16x8 onesb;
#pragma unroll
  for (int j = 0; j < 8; j++) onesb[j] = (__bf16)1.0f;

#pragma unroll
  for (int half = 0; half < 2; half++) {
    const int qi = half ? blockIdx.x : (31 - blockIdx.x);  // longest first
    const int sq0 = qi * 64;
    const int nT = qi + 1;
    const int wrow = sq0 + wave * 16;              // this wave's first Q row

    const int spos = wrow + lm;                    // sequence position (< S_)
    const u16* qptr = Q + ((size_t)(b * S_ + wrow + lm) * H_ + h) * D_;
    bf16x8 qf[4];
#pragma unroll
    for (int ks = 0; ks < 2; ks++) {
      bf16x8 a = *(const bf16x8*)(qptr + ks * 32 + quad * 8);
      bf16x8 c = *(const bf16x8*)(qptr + (ks + 2) * 32 + quad * 8);
#pragma unroll
      for (int j = 0; j < 8; j++) {
        int d = ks * 32 + quad * 8 + j;
        float ang = (float)spos * __expf(-0.14391156831212787f * (float)d);
        float sn, cs;
        sincosf(ang, &sn, &cs);
        float x0 = (float)a[j], x1 = (float)c[j];
        const float scale = 0.08838834764831845f;
        qf[ks][j]     = (__bf16)((x0 * cs - x1 * sn) * scale);
        qf[ks + 2][j] = (__bf16)((x1 * cs + x0 * sn) * scale);
      }
    }

    f32x4 o[8];
    f32x4 lacc = {0.f, 0.f, 0.f, 0.f};
#pragma unroll
    for (int i = 0; i < 8; i++) o[i] = f32x4{0.f, 0.f, 0.f, 0.f};

    __syncthreads();   // previous half fully done with Ksh/Vsh/Psh
#pragma unroll
    for (int i = 0; i < 4; i++)
      gload_lds16(Kbase + offK[i], &Ksh[0][ldsOff[i]]);

    for (int t = 0; t < nT; t++) {
      const int sk0 = t << 6;
      const bool act = (sk0 <= wrow + 15);         // skip fully-masked tiles
      __syncthreads();   // (A) K(t) drained; prev PV/P reads done

      if (t + 1 < nT) {
        const u16* kg = Kbase + (size_t)(t + 1) * 64 * 128;
        u16* kb_next = &Ksh[(t + 1) & 1][0];
#pragma unroll
        for (int i = 0; i < 4; i++)
          gload_lds16(kg + offK[i], kb_next + ldsOff[i]);
      }
#pragma unroll
      for (int i = 0; i < 4; i++)
        gload_lds16(Vbase + sk0 + offV[i], &Vsh[ldsOff[i]]);

      f32x4 sc[4];
      if (act) {
        const u16* kbuf = &Ksh[t & 1][0];
#pragma unroll
        for (int nt = 0; nt < 4; nt++) sc[nt] = f32x4{0.f, 0.f, 0.f, 0.f};
#pragma unroll
        for (int ks = 0; ks < 4; ks++) {
#pragma unroll
          for (int nt = 0; nt < 4; nt++) {
            int R = nt * 16 + lm;
            bf16x8 kb = *(const bf16x8*)(kbuf + R * 128 + (((ks * 4 + quad) ^ (R & 7)) * 8));
            sc[nt] = __builtin_amdgcn_mfma_f32_16x16x32_bf16(qf[ks], kb, sc[nt], 0, 0, 0);
          }
        }
#pragma unroll
        for (int nt = 0; nt < 4; nt++)
#pragma unroll
          for (int r = 0; r < 4; r++) {
            float p = __expf(sc[nt][r]);
            int kc = sk0 + nt * 16 + lm;
            int qr = wrow + quad * 4 + r;
            sc[nt][r] = (kc > qr) ? 0.f : p;
          }
#pragma unroll
        for (int nt = 0; nt < 4; nt++)
#pragma unroll
          for (int r = 0; r < 4; r++) {
            int p = quad * 4 + r;
            int c = nt * 2 + (lm >> 3);
            pw[p * 64 + ((c ^ (p & 7)) * 8) + (lm & 7)] = f2bf(sc[nt][r]);
          }
      }

      __syncthreads();   // (B) vmcnt drain: K(t+1), V(t) resident; P visible

      if (act) {
#pragma unroll
        for (int ks = 0; ks < 2; ks++) {
          int pr = lm;
          bf16x8 pa = *(const bf16x8*)(pw + pr * 64 + (((ks * 4 + quad) ^ (pr & 7)) * 8));
          lacc = __builtin_amdgcn_mfma_f32_16x16x32_bf16(pa, onesb, lacc, 0, 0, 0);
#pragma unroll
          for (int d8 = 0; d8 < 8; d8++) {
            int R = d8 * 16 + lm;
            bf16x8 vb = *(const bf16x8*)(Vsh + R * 64 + (((ks * 4 + quad) ^ (R & 7)) * 8));
            o[d8] = __builtin_amdgcn_mfma_f32_16x16x32_bf16(pa, vb, o[d8], 0, 0, 0);
          }
        }
      }
    }

    float inv[4];
#pragma unroll
    for (int r = 0; r < 4; r++) inv[r] = 1.0f / lacc[r];
#pragma unroll
    for (int d8 = 0; d8 < 8; d8++)
#pragma unroll
      for (int r = 0; r < 4; r++) {
        int srow = wrow + quad * 4 + r;
        O[((size_t)(b * S_ + srow) * H_ + h) * D_ + d8 * 16 + lm] = f2bf(o[d8][r] * inv[r]);
      }
  }
}

extern "C" void kernel_launch(void* const* d_in, const int* in_sizes, int n_in,
                              void* d_out, int out_size, void* d_ws, size_t ws_size,
                              hipStream_t stream) {
  const float* x  = (const float*)d_in[0];
  const float* Wq = (const float*)d_in[1];
  const float* Wk = (const float*)d_in[2];
  const float* Wv = (const float*)d_in[3];
  const float* Wo = (const float*)d_in[4];
  float* out = (float*)d_out;
  char* ws = (char*)d_ws;
  u16* Xb  = (u16*)(ws);                         // 16 MiB  bf16 x        [4096][2048]
  u16* WqT = (u16*)(ws + (16ull << 20));         //  8 MiB
  u16* WkT = (u16*)(ws + (24ull << 20));         //  2 MiB
  u16* WvT = (u16*)(ws + (26ull << 20));         //  2 MiB
  u16* WoT = (u16*)(ws + (28ull << 20));         //  8 MiB
  u16* Qb  = (u16*)(ws + (36ull << 20));         // 16 MiB  Q raw proj    [4096][16][128]
  u16* Kb  = (u16*)(ws + (52ull << 20));         //  4 MiB  K raw proj    [4096][4][128]
  u16* Vb  = (u16*)(ws + (56ull << 20));         //  4 MiB  V             [4096][4][128]
  u16* Vt  = (u16*)(ws + (60ull << 20));         //  4 MiB  V^T           [2][4][128][2048]
  u16* Ob  = (u16*)(ws + (64ull << 20));         // 16 MiB  attn out      [4096][16][128]
  u16* Kp  = (u16*)(ws + (80ull << 20));         //  4 MiB  K roped+packed[2][4][2048][128]

  static bool attr_set = false;
  if (!attr_set) {
    hipFuncSetAttribute((const void*)gemm256_qkv,
                        hipFuncAttributeMaxDynamicSharedMemorySize, 131072);
    hipFuncSetAttribute((const void*)gemm256_wo,
                        hipFuncAttributeMaxDynamicSharedMemorySize, 131072);
    attr_set = true;
  }

  dim3 tb32(32, 8);

  convert_fp32_bf16<<<dim3(M_ * E_ / 4 / 256), 256, 0, stream>>>((const float4*)x, (uint2*)Xb, M_ * E_ / 4);
  transpose_conv_w<<<dim3(2048 / 32, 2048 / 32), tb32, 0, stream>>>(Wq, WqT, E_, H_ * D_);
  transpose_conv_w<<<dim3(512 / 32, 2048 / 32), tb32, 0, stream>>>(Wk, WkT, E_, KV_ * D_);
  transpose_conv_w<<<dim3(512 / 32, 2048 / 32), tb32, 0, stream>>>(Wv, WvT, E_, KV_ * D_);
  transpose_conv_w<<<dim3(2048 / 32, 2048 / 32), tb32, 0, stream>>>(Wo, WoT, E_, E_);

  gemm256_qkv<<<dim3(12, M_ / 256), 512, 131072, stream>>>(Xb, WqT, WkT, WvT, Qb, Kb, Vb);

  rope_k_repack<<<dim3(M_ * KV_ * 64 / 256), 256, 0, stream>>>(Kb, Kp, M_ * KV_ * 64);

  transpose_v<<<dim3(S_ / 32, D_ / 32, B_ * KV_), tb32, 0, stream>>>(Vb, Vt);

  attn_kernel<<<dim3(16, H_, B_), 256, 0, stream>>>(Qb, Kp, Vt, Ob);

  gemm256_wo<<<dim3(2048 / 256, M_ / 256), 512, 131072, stream>>>(Ob, WoT, out);
}

// Round 2
// 313.636 us; speedup vs baseline: 1.0091x; 1.0091x over previous
//
#include <hip/hip_runtime.h>
#include <stdint.h>

#define B_ 2
#define S_ 2048
#define E_ 2048
#define H_ 16
#define KV_ 4
#define D_ 128
#define G_ (H_ / KV_)
#define M_ (B_ * S_)   // 4096 rows (b*s)

typedef unsigned short u16;
typedef unsigned int u32;
typedef __bf16 bf16x8 __attribute__((ext_vector_type(8)));
typedef float f32x4 __attribute__((ext_vector_type(4)));

__device__ __forceinline__ u16 f2bf(float f) {
  __bf16 h = (__bf16)f;            // v_cvt RNE
  return *(u16*)&h;
}
__device__ __forceinline__ float bf2f(u16 x) {
  return __uint_as_float(((u32)x) << 16);
}
__device__ __forceinline__ void store_c(u16* p, float v) { *p = f2bf(v); }
__device__ __forceinline__ void store_c(float* p, float v) { *p = v; }

// async global->LDS, 16B per lane; LDS dest = wave-uniform base + lane*16
__device__ __forceinline__ void gload_lds16(const u16* g, u16* lds) {
  __builtin_amdgcn_global_load_lds((const __attribute__((address_space(1))) u32*)g,
                                   (__attribute__((address_space(3))) u32*)lds,
                                   16, 0, 0);
}

// ---------------- elementwise fp32 -> bf16 ----------------
__global__ __launch_bounds__(256) void convert_fp32_bf16(const float4* __restrict__ x,
                                                         uint2* __restrict__ o, int n4) {
  int i = blockIdx.x * 256 + threadIdx.x;
  if (i >= n4) return;
  float4 v = x[i];
  uint2 r;
  r.x = (u32)f2bf(v.x) | ((u32)f2bf(v.y) << 16);
  r.y = (u32)f2bf(v.z) | ((u32)f2bf(v.w) << 16);
  o[i] = r;
}

// ---------------- W (K x N) fp32 -> Wt (N x K) bf16 ----------------
__global__ __launch_bounds__(256) void transpose_conv_w(const float* __restrict__ W,
                                                        u16* __restrict__ Wt,
                                                        int Kdim, int Ndim) {
  __shared__ float tile[32][33];
  int n0 = blockIdx.x * 32, k0 = blockIdx.y * 32;
  int tx = threadIdx.x, ty = threadIdx.y;
#pragma unroll
  for (int i = 0; i < 4; i++) {
    int r = ty + i * 8;
    tile[r][tx] = W[(size_t)(k0 + r) * Ndim + n0 + tx];
  }
  __syncthreads();
#pragma unroll
  for (int i = 0; i < 4; i++) {
    int r = ty + i * 8;
    Wt[(size_t)(n0 + r) * Kdim + k0 + tx] = f2bf(tile[tx][r]);
  }
}

// ---------------- V [B][S][KV][D] -> Vt [B][KV][D][S] (bf16) ----------------
__global__ __launch_bounds__(256) void transpose_v(const u16* __restrict__ V,
                                                   u16* __restrict__ Vt) {
  __shared__ u16 tile[32][33];
  int bkv = blockIdx.z;
  int b = bkv / KV_, kv = bkv % KV_;
  int s0 = blockIdx.x * 32, d0 = blockIdx.y * 32;
  int tx = threadIdx.x, ty = threadIdx.y;
#pragma unroll
  for (int i = 0; i < 4; i++) {
    int r = ty + i * 8;  // s within tile
    tile[r][tx] = V[((size_t)((b * S_ + s0 + r) * KV_ + kv)) * D_ + d0 + tx];
  }
  __syncthreads();
#pragma unroll
  for (int i = 0; i < 4; i++) {
    int r = ty + i * 8;  // d within tile
    Vt[((size_t)(b * KV_ + kv) * D_ + d0 + r) * S_ + s0 + tx] = tile[tx][r];
  }
}

// ---------------- RoPE K + repack [row][KV][128] -> [b][kv][s][128] ----------------
__global__ __launch_bounds__(256) void rope_k_repack(const u16* __restrict__ Kin,
                                                     u16* __restrict__ Kp, int total) {
  int idx = blockIdx.x * 256 + threadIdx.x;
  if (idx >= total) return;
  int d = idx & 63;
  int rem = idx >> 6;
  int kv = rem % KV_;
  int row = rem / KV_;
  int b = row >> 11;           // row / S_
  int spos = row & (S_ - 1);
  size_t src = ((size_t)row * KV_ + kv) * D_ + d;
  float x0 = bf2f(Kin[src]);
  float x1 = bf2f(Kin[src + 64]);
  float ang = (float)spos * expf(-0.14391156831212787f * (float)d);
  float sn, cs;
  sincosf(ang, &sn, &cs);
  size_t dst = ((size_t)((b * KV_ + kv) * S_ + spos)) * D_ + d;
  Kp[dst]      = f2bf(x0 * cs - x1 * sn);
  Kp[dst + 64] = f2bf(x1 * cs + x0 * sn);
}

// =====================================================================
// 256x256 8-phase bf16 GEMM (m201 template, plain HIP):
//   C(MxN) = A(MxK) * Bt(NxK)^T   (unchanged from round 1)
// =====================================================================
template <typename CT>
__device__ __forceinline__ void gemm256_body(const u16* __restrict__ A,
                                             const u16* __restrict__ Bt,
                                             CT* __restrict__ C,
                                             int Kdim, int Ndim, int m0, int n0) {
  extern __shared__ __align__(16) u16 smem[];   // 65536 u16 = 128 KiB
  const int tid  = threadIdx.x;
  const int lane = tid & 63;
  const int wave = tid >> 6;          // 0..7
  const int wm   = wave >> 2;         // 0..1  M-half of the tile
  const int wn   = wave & 3;          // 0..3  N-quarter
  const int bh   = wn >> 1;           // which B half this wave reads
  const int nb   = (wn & 1) * 64;     // row offset inside B half
  const int quad = lane >> 4, lm = lane & 15;

  int soff[2], sldb[2];
#pragma unroll
  for (int i = 0; i < 2; i++) {
    int cc  = i * 512 + tid;          // 16B chunk id in [0,1024)
    int row = cc >> 3;                // 8 chunks per 128B row
    int q   = (cc & 7) ^ (row & 7);   // inverse-swizzled source chunk
    soff[i] = row * Kdim + q * 8;     // u16 elements
    sldb[i] = (i * 512 + wave * 64) * 8;  // wave-uniform LDS u16 base
  }
  auto STAGE = [&](const u16* g, u16* l) {
    gload_lds16(g + soff[0], l + sldb[0]);
    gload_lds16(g + soff[1], l + sldb[1]);
  };

  int cs0 = ((0 + quad) ^ (lm & 7)) * 8;
  int cs1 = ((4 + quad) ^ (lm & 7)) * 8;

  const u16* Ag = A  + (size_t)m0 * Kdim;
  const u16* Bg = Bt + (size_t)n0 * Kdim;
  const size_t hstep = (size_t)128 * Kdim;  // half-tile row step

  f32x4 acc[8][4];
  f32x4 zero = {0.f, 0.f, 0.f, 0.f};
#pragma unroll
  for (int m = 0; m < 8; m++)
#pragma unroll
    for (int n = 0; n < 4; n++) acc[m][n] = zero;

  const int NKT = Kdim >> 6;

  STAGE(Bg,             smem + 32768 + 0 * 8192);  // t0 B0
  STAGE(Ag,             smem + 0 * 8192);          // t0 A0
  STAGE(Ag + hstep,     smem + 1 * 8192);          // t0 A1
  STAGE(Bg + hstep,     smem + 32768 + 1 * 8192);  // t0 B1
  STAGE(Bg + 64,        smem + 32768 + 2 * 8192);  // t1 B0
  STAGE(Ag + 64,        smem + 2 * 8192);          // t1 A0
  STAGE(Ag + hstep + 64, smem + 3 * 8192);         // t1 A1
  asm volatile("s_waitcnt vmcnt(6)" ::: "memory"); // t0 fully resident (own ops)
  __builtin_amdgcn_s_barrier();                    // -> all waves' ops resident

  for (int kt = 0; kt < NKT; ++kt) {
    const int cur = kt & 1;
    const u16* regA = smem + (cur * 2 + wm) * 8192;
    const u16* regB = smem + 32768 + (cur * 2 + bh) * 8192;
    bf16x8 af[4][2], bf[4][2];

    // ---------- phase 0 ----------
#pragma unroll
    for (int n = 0; n < 4; n++) {
      bf[n][0] = *(const bf16x8*)(regB + (nb + n * 16 + lm) * 64 + cs0);
      bf[n][1] = *(const bf16x8*)(regB + (nb + n * 16 + lm) * 64 + cs1);
    }
#pragma unroll
    for (int m = 0; m < 4; m++) {
      af[m][0] = *(const bf16x8*)(regA + (m * 16 + lm) * 64 + cs0);
      af[m][1] = *(const bf16x8*)(regA + (m * 16 + lm) * 64 + cs1);
    }
    if (kt + 1 < NKT)
      STAGE(Bg + hstep + (size_t)(kt + 1) * 64,
            smem + 32768 + (((kt + 1) & 1) * 2 + 1) * 8192);
    asm volatile("s_waitcnt lgkmcnt(0)" ::: "memory");
    __builtin_amdgcn_s_barrier();
    __builtin_amdgcn_s_setprio(1);
#pragma unroll
    for (int m = 0; m < 4; m++)
#pragma unroll
      for (int n = 0; n < 2; n++) {
        acc[m][n] = __builtin_amdgcn_mfma_f32_16x16x32_bf16(af[m][0], bf[n][0], acc[m][n], 0, 0, 0);
        acc[m][n] = __builtin_amdgcn_mfma_f32_16x16x32_bf16(af[m][1], bf[n][1], acc[m][n], 0, 0, 0);
      }
    __builtin_amdgcn_s_setprio(0);
    __builtin_amdgcn_s_barrier();

    // ---------- phase 1 ----------
    if (kt + 2 < NKT)
      STAGE(Bg + (size_t)(kt + 2) * 64, smem + 32768 + (cur * 2 + 0) * 8192);
    __builtin_amdgcn_s_barrier();
    __builtin_amdgcn_s_setprio(1);
#pragma unroll
    for (int m = 0; m < 4; m++)
#pragma unroll
      for (int n = 2; n < 4; n++) {
        acc[m][n] = __builtin_amdgcn_mfma_f32_16x16x32_bf16(af[m][0], bf[n][0], acc[m][n], 0, 0, 0);
        acc[m][n] = __builtin_amdgcn_mfma_f32_16x16x32_bf16(af[m][1], bf[n][1], acc[m][n], 0, 0, 0);
      }
    __builtin_amdgcn_s_setprio(0);
    __builtin_amdgcn_s_barrier();

    // ---------- phase 2 ----------
#pragma unroll
    for (int m = 0; m < 4; m++) {
      af[m][0] = *(const bf16x8*)(regA + ((m + 4) * 16 + lm) * 64 + cs0);
      af[m][1] = *(const bf16x8*)(regA + ((m + 4) * 16 + lm) * 64 + cs1);
    }
    asm volatile("s_waitcnt lgkmcnt(0)" ::: "memory");
    __builtin_amdgcn_s_barrier();
    __builtin_amdgcn_s_setprio(1);
#pragma unroll
    for (int m = 0; m < 4; m++)
#pragma unroll
      for (int n = 0; n < 2; n++) {
        acc[m + 4][n] = __builtin_amdgcn_mfma_f32_16x16x32_bf16(af[m][0], bf[n][0], acc[m + 4][n], 0, 0, 0);
        acc[m + 4][n] = __builtin_amdgcn_mfma_f32_16x16x32_bf16(af[m][1], bf[n][1], acc[m + 4][n], 0, 0, 0);
      }
    __builtin_amdgcn_s_setprio(0);
    __builtin_amdgcn_s_barrier();

    // ---------- phase 3 ----------
    if (kt + 2 < NKT) {
      STAGE(Ag + (size_t)(kt + 2) * 64,         smem + (cur * 2 + 0) * 8192);
      STAGE(Ag + hstep + (size_t)(kt + 2) * 64, smem + (cur * 2 + 1) * 8192);
    }
    __builtin_amdgcn_s_setprio(1);
#pragma unroll
    for (int m = 0; m < 4; m++)
#pragma unroll
      for (int n = 2; n < 4; n++) {
        acc[m + 4][n] = __builtin_amdgcn_mfma_f32_16x16x32_bf16(af[m][0], bf[n][0], acc[m + 4][n], 0, 0, 0);
        acc[m + 4][n] = __builtin_amdgcn_mfma_f32_16x16x32_bf16(af[m][1], bf[n][1], acc[m + 4][n], 0, 0, 0);
      }
    __builtin_amdgcn_s_setprio(0);
    asm volatile("s_waitcnt vmcnt(6)" ::: "memory");  // next tile fully resident
    __builtin_amdgcn_s_barrier();
  }

#pragma unroll
  for (int m = 0; m < 8; m++) {
    const int row = m0 + wm * 128 + m * 16 + quad * 4;
#pragma unroll
    for (int n = 0; n < 4; n++) {
      const int col = n0 + wn * 64 + n * 16 + lm;
#pragma unroll
      for (int r = 0; r < 4; r++)
        store_c(C + (size_t)(row + r) * Ndim + col, acc[m][n][r]);
    }
  }
}

// fused Q/K/V projection, 256^2 tiles: x 0..7 -> Q, 8..9 -> K, 10..11 -> V
__global__ __launch_bounds__(512, 2) void gemm256_qkv(const u16* __restrict__ A,
                                                      const u16* __restrict__ WqT,
                                                      const u16* __restrict__ WkT,
                                                      const u16* __restrict__ WvT,
                                                      u16* __restrict__ Qb,
                                                      u16* __restrict__ Kb,
                                                      u16* __restrict__ Vb) {
  int bx = blockIdx.x;
  const u16* Bt;
  u16* C;
  int n0, Ndim;
  if (bx < 8)       { Bt = WqT; C = Qb; n0 = bx * 256;        Ndim = 2048; }
  else if (bx < 10) { Bt = WkT; C = Kb; n0 = (bx - 8) * 256;  Ndim = 512; }
  else              { Bt = WvT; C = Vb; n0 = (bx - 10) * 256; Ndim = 512; }
  gemm256_body<u16>(A, Bt, C, 2048, Ndim, blockIdx.y * 256, n0);
}

__global__ __launch_bounds__(512, 2) void gemm256_wo(const u16* __restrict__ A,
                                                     const u16* __restrict__ Bt,
                                                     float* __restrict__ C) {
  gemm256_body<float>(A, Bt, C, 2048, 2048, blockIdx.y * 256, blockIdx.x * 256);
}

// ---------------- causal GQA flash attention, v6 ----------------
// v5 + T3/T4: K AND V double-buffered; both __syncthreads() per K-tile
// replaced by raw s_barrier + counted s_waitcnt vmcnt(8) (never a full
// drain in the loop).  Tile t's 8 DMA ops are issued during iteration
// t-1, so the consume-wait is ~0 in steady state.  T5 setprio around the
// MFMA clusters.  Grid is (H, qpair, B) so id%8 = h%8: each XCD's L2
// holds exactly its 2 kh x 2 b = 4 MB of K/V (was: every XCD touched all
// 8 MB -> L2 thrash, 26 MB HBM over-fetch).
// LDS 72 KB -> still 2 blocks/CU.
__global__ __launch_bounds__(256, 2) void attn_kernel(const u16* __restrict__ Q,
                                                      const u16* __restrict__ Kp,
                                                      const u16* __restrict__ Vt,
                                                      u16* __restrict__ O) {
  __shared__ __align__(16) u16 Ksh[2][64 * 128];   // 2 x 16 KB
  __shared__ __align__(16) u16 Vsh[2][128 * 64];   // 2 x 16 KB
  __shared__ __align__(16) u16 Psh[4][16 * 64];    // 8 KB, per-wave

  const int tid = threadIdx.x;
  const int lane = tid & 63;
  const int wave = tid >> 6;                       // 0..3
  const int quad = lane >> 4, lm = lane & 15;
  const int b = blockIdx.z, h = blockIdx.x;        // h on x for XCD locality
  const int kh = h / G_;

  const u16* Kbase = Kp + (size_t)(b * KV_ + kh) * S_ * D_;
  const u16* Vbase = Vt + (size_t)(b * KV_ + kh) * D_ * S_;
  u16* pw = &Psh[wave][0];

  // DMA source offsets (XOR-swizzled: LDS chunk idx holds global chunk c^(row&7))
  int offK[4], offV[4], ldsOff[4];
#pragma unroll
  for (int i = 0; i < 4; i++) {
    int idx = (wave * 4 + i) * 64 + lane;          // [0,1024) 16B-chunk id
    int rK = idx >> 4;                             // K row (key), 16 chunks/row
    int cK = (idx & 15) ^ (rK & 7);
    offK[i] = rK * 128 + cK * 8;
    int rV = idx >> 3;                             // V^T row (d), 8 chunks/row
    int cV = (idx & 7) ^ (rV & 7);
    offV[i] = rV * S_ + cV * 8;
    ldsOff[i] = (wave * 4 + i) * 512;              // u16
  }

  bf16x8 onesb;
#pragma unroll
  for (int j = 0; j < 8; j++) onesb[j] = (__bf16)1.0f;

#pragma unroll
  for (int half = 0; half < 2; half++) {
    const int qi = half ? blockIdx.y : (31 - blockIdx.y);  // longest first
    const int sq0 = qi * 64;
    const int nT = qi + 1;
    const int wrow = sq0 + wave * 16;              // this wave's first Q row

    // ---- Q fragment load + fused RoPE + 1/sqrt(D) scale ----
    const int spos = wrow + lm;                    // sequence position (< S_)
    const u16* qptr = Q + ((size_t)(b * S_ + wrow + lm) * H_ + h) * D_;
    bf16x8 qf[4];
#pragma unroll
    for (int ks = 0; ks < 2; ks++) {
      bf16x8 a = *(const bf16x8*)(qptr + ks * 32 + quad * 8);
      bf16x8 c = *(const bf16x8*)(qptr + (ks + 2) * 32 + quad * 8);
#pragma unroll
      for (int j = 0; j < 8; j++) {
        int d = ks * 32 + quad * 8 + j;
        float ang = (float)spos * __expf(-0.14391156831212787f * (float)d);
        float sn, cs;
        sincosf(ang, &sn, &cs);
        float x0 = (float)a[j], x1 = (float)c[j];
        const float scale = 0.08838834764831845f;
        qf[ks][j]     = (__bf16)((x0 * cs - x1 * sn) * scale);
        qf[ks + 2][j] = (__bf16)((x1 * cs + x0 * sn) * scale);
      }
    }

    f32x4 o[8];
    f32x4 lacc = {0.f, 0.f, 0.f, 0.f};
#pragma unroll
    for (int i = 0; i < 8; i++) o[i] = f32x4{0.f, 0.f, 0.f, 0.f};

    __syncthreads();   // previous half fully done with Ksh/Vsh/Psh (full drain, 2x/kernel)

    // prologue: DMA K(0),V(0) into buffer 0
#pragma unroll
    for (int i = 0; i < 4; i++)
      gload_lds16(Kbase + offK[i], &Ksh[0][ldsOff[i]]);
#pragma unroll
    for (int i = 0; i < 4; i++)
      gload_lds16(Vbase + offV[i], &Vsh[0][ldsOff[i]]);

    for (int t = 0; t < nT; t++) {
      const int sk0 = t << 6;
      const bool act = (sk0 <= wrow + 15);         // skip fully-masked tiles

      // (#1) all waves done reading buffers parity (t+1)&1 (tile t-1)
      __builtin_amdgcn_s_barrier();

      if (t + 1 < nT) {
        // issue t+1 batch (8 vmem ops) into parity (t+1)&1
        const u16* kg = Kbase + (size_t)(t + 1) * 64 * 128;
        const u16* vg = Vbase + (t + 1) * 64;
        u16* kb_next = &Ksh[(t + 1) & 1][0];
        u16* vb_next = &Vsh[(t + 1) & 1][0];
#pragma unroll
        for (int i = 0; i < 4; i++)
          gload_lds16(kg + offK[i], kb_next + ldsOff[i]);
#pragma unroll
        for (int i = 0; i < 4; i++)
          gload_lds16(vg + offV[i], vb_next + ldsOff[i]);
        // counted wait: allow the 8 just-issued ops to stay in flight;
        // everything older (tile t's batch) has retired.
        asm volatile("s_waitcnt vmcnt(8)" ::: "memory");
      } else {
        asm volatile("s_waitcnt vmcnt(0)" ::: "memory");
      }

      // (#2) tile t resident for ALL waves
      __builtin_amdgcn_s_barrier();
      __builtin_amdgcn_sched_barrier(0);   // no load hoisting above the barrier

      if (act) {
        // S = Q K^T (scale prefolded into Q)
        const u16* kbuf = &Ksh[t & 1][0];
        f32x4 sc[4];
#pragma unroll
        for (int nt = 0; nt < 4; nt++) sc[nt] = f32x4{0.f, 0.f, 0.f, 0.f};
        __builtin_amdgcn_s_setprio(1);
#pragma unroll
        for (int ks = 0; ks < 4; ks++) {
#pragma unroll
          for (int nt = 0; nt < 4; nt++) {
            int R = nt * 16 + lm;
            bf16x8 kb = *(const bf16x8*)(kbuf + R * 128 + (((ks * 4 + quad) ^ (R & 7)) * 8));
            sc[nt] = __builtin_amdgcn_mfma_f32_16x16x32_bf16(qf[ks], kb, sc[nt], 0, 0, 0);
          }
        }
        __builtin_amdgcn_s_setprio(0);
        // P = exp(S) with causal zeroing (max-free; |s| <~ 6)
#pragma unroll
        for (int nt = 0; nt < 4; nt++)
#pragma unroll
          for (int r = 0; r < 4; r++) {
            float p = __expf(sc[nt][r]);
            int kc = sk0 + nt * 16 + lm;
            int qr = wrow + quad * 4 + r;
            sc[nt][r] = (kc > qr) ? 0.f : p;
          }
        // P: C-layout -> per-wave swizzled LDS (A-layout source for PV)
#pragma unroll
        for (int nt = 0; nt < 4; nt++)
#pragma unroll
          for (int r = 0; r < 4; r++) {
            int p = quad * 4 + r;
            int c = nt * 2 + (lm >> 3);
            pw[p * 64 + ((c ^ (p & 7)) * 8) + (lm & 7)] = f2bf(sc[nt][r]);
          }
        // O += P @ V ; l += P @ ones   (per-wave Psh: within-wave lgkm dep only)
        const u16* vbuf = &Vsh[t & 1][0];
        __builtin_amdgcn_s_setprio(1);
#pragma unroll
        for (int ks = 0; ks < 2; ks++) {
          int pr = lm;
          bf16x8 pa = *(const bf16x8*)(pw + pr * 64 + (((ks * 4 + quad) ^ (pr & 7)) * 8));
          lacc = __builtin_amdgcn_mfma_f32_16x16x32_bf16(pa, onesb, lacc, 0, 0, 0);
#pragma unroll
          for (int d8 = 0; d8 < 8; d8++) {
            int R = d8 * 16 + lm;
            bf16x8 vb = *(const bf16x8*)(vbuf + R * 64 + (((ks * 4 + quad) ^ (R & 7)) * 8));
            o[d8] = __builtin_amdgcn_mfma_f32_16x16x32_bf16(pa, vb, o[d8], 0, 0, 0);
          }
        }
        __builtin_amdgcn_s_setprio(0);
      }
    }

    float inv[4];
#pragma unroll
    for (int r = 0; r < 4; r++) inv[r] = 1.0f / lacc[r];
#pragma unroll
    for (int d8 = 0; d8 < 8; d8++)
#pragma unroll
      for (int r = 0; r < 4; r++) {
        int srow = wrow + quad * 4 + r;
        O[((size_t)(b * S_ + srow) * H_ + h) * D_ + d8 * 16 + lm] = f2bf(o[d8][r] * inv[r]);
      }
  }
}

extern "C" void kernel_launch(void* const* d_in, const int* in_sizes, int n_in,
                              void* d_out, int out_size, void* d_ws, size_t ws_size,
                              hipStream_t stream) {
  const float* x  = (const float*)d_in[0];
  const float* Wq = (const float*)d_in[1];
  const float* Wk = (const float*)d_in[2];
  const float* Wv = (const float*)d_in[3];
  const float* Wo = (const float*)d_in[4];
  float* out = (float*)d_out;
  char* ws = (char*)d_ws;
  u16* Xb  = (u16*)(ws);                         // 16 MiB  bf16 x        [4096][2048]
  u16* WqT = (u16*)(ws + (16ull << 20));         //  8 MiB
  u16* WkT = (u16*)(ws + (24ull << 20));         //  2 MiB
  u16* WvT = (u16*)(ws + (26ull << 20));         //  2 MiB
  u16* WoT = (u16*)(ws + (28ull << 20));         //  8 MiB
  u16* Qb  = (u16*)(ws + (36ull << 20));         // 16 MiB  Q raw proj    [4096][16][128]
  u16* Kb  = (u16*)(ws + (52ull << 20));         //  4 MiB  K raw proj    [4096][4][128]
  u16* Vb  = (u16*)(ws + (56ull << 20));         //  4 MiB  V             [4096][4][128]
  u16* Vt  = (u16*)(ws + (60ull << 20));         //  4 MiB  V^T           [2][4][128][2048]
  u16* Ob  = (u16*)(ws + (64ull << 20));         // 16 MiB  attn out      [4096][16][128]
  u16* Kp  = (u16*)(ws + (80ull << 20));         //  4 MiB  K roped+packed[2][4][2048][128]

  static bool attr_set = false;
  if (!attr_set) {
    hipFuncSetAttribute((const void*)gemm256_qkv,
                        hipFuncAttributeMaxDynamicSharedMemorySize, 131072);
    hipFuncSetAttribute((const void*)gemm256_wo,
                        hipFuncAttributeMaxDynamicSharedMemorySize, 131072);
    attr_set = true;
  }

  dim3 tb32(32, 8);

  convert_fp32_bf16<<<dim3(M_ * E_ / 4 / 256), 256, 0, stream>>>((const float4*)x, (uint2*)Xb, M_ * E_ / 4);
  transpose_conv_w<<<dim3(2048 / 32, 2048 / 32), tb32, 0, stream>>>(Wq, WqT, E_, H_ * D_);
  transpose_conv_w<<<dim3(512 / 32, 2048 / 32), tb32, 0, stream>>>(Wk, WkT, E_, KV_ * D_);
  transpose_conv_w<<<dim3(512 / 32, 2048 / 32), tb32, 0, stream>>>(Wv, WvT, E_, KV_ * D_);
  transpose_conv_w<<<dim3(2048 / 32, 2048 / 32), tb32, 0, stream>>>(Wo, WoT, E_, E_);

  gemm256_qkv<<<dim3(12, M_ / 256), 512, 131072, stream>>>(Xb, WqT, WkT, WvT, Qb, Kb, Vb);

  rope_k_repack<<<dim3(M_ * KV_ * 64 / 256), 256, 0, stream>>>(Kb, Kp, M_ * KV_ * 64);

  transpose_v<<<dim3(S_ / 32, D_ / 32, B_ * KV_), tb32, 0, stream>>>(Vb, Vt);

  attn_kernel<<<dim3(H_, 16, B_), 256, 0, stream>>>(Qb, Kp, Vt, Ob);

  gemm256_wo<<<dim3(2048 / 256, M_ / 256), 512, 131072, stream>>>(Ob, WoT, out);
}